// Round 3
// baseline (1334.207 us; speedup 1.0000x reference)
//
#include <hip/hip_runtime.h>

// ---------------------------------------------------------------------------
// RGCN (basis decomposition), 2 layers. N=50000, E=1e6, H=128, O=64, R=16.
// Round 12: round 11 (no-drain barrier) was NULL -> latency wasn't the wall.
// Arithmetic: ~2000 cy CU-pipe work per block-phase matches MfmaUtil 19.5%
// exactly, and layer2 (half the MFMA) runs the SAME time as layer1 -> the
// per-phase agg machinery (f2bf pack ~64 VALU, ys LDS round-trip, 10 MFMAs
// on a 1.25%-dense P matrix, handler scatter/clear) is the cost, not GEMM1.
// Changes:
//  - DELETE ys/pmat/agg-MFMA/handler entirely. Aggregation is now direct
//    ds_add_f32: keep GEMM1 dacc (f32) in regs, multiply by f32 norm, and
//    atomicAdd into lds_out[66][OUT+4] f32 (pad -> dloc*4 bank spread,
//    ~2-way conflicts = free). Per-row {dloc,norm} staged per chunk in tiny
//    LDS arrays (uchar[32] + float[32], double-buffered).
//  - Messages stay f32 (better accuracy than bf16 ys path). pacc regs gone.
//  - Stale xs rows are masked per-lane at the ds_add (row < nRows), so xs
//    zero-init no longer needed; rows never pollute other rows (MFMA row
//    independence).
//  - Layer2 LDS ~36KB -> 4 blocks/CU (launch_bounds 4); layer1 ~53.5KB
//    stays 3 blocks/CU (desc as int2, dloc as uchar to fit under 160/3).
// Kept: binning, xs staging + depth-3 register pipeline, barrier_nodrain,
// setprio on GEMM1. GEMM1 MFMA layout identical to rounds 3-11 (passing).
// ---------------------------------------------------------------------------

typedef short bf16x8 __attribute__((ext_vector_type(8)));
typedef float f32x4 __attribute__((ext_vector_type(4)));

#define RELS 16
#define HDIM 128
#define DSTBLK 66
#define CHUNK 32
#define MAXBINS 12288
#define MAXCH 96  // chunks/block: mean ~49; needs edges>2592 (35 sigma) to overflow

__device__ inline unsigned short f2bf(float f) {
  unsigned int u = __float_as_uint(f);
  unsigned int r = u + 0x7FFFu + ((u >> 16) & 1u);
  return (unsigned short)(r >> 16);
}

// Workgroup barrier WITHOUT the vmcnt(0) drain __syncthreads() emits.
// Correct here because inter-wave communication is exclusively through LDS:
// lgkmcnt(0) makes all DS writes/atomics visible; in-flight global loads only
// feed this wave's registers (compiler inserts counted vmcnt at first use).
__device__ inline void barrier_nodrain() {
  __builtin_amdgcn_sched_barrier(0);
  asm volatile("s_waitcnt lgkmcnt(0)" ::: "memory");
  __builtin_amdgcn_s_barrier();
  __builtin_amdgcn_sched_barrier(0);
}

__global__ void cvt_bf16(const float* __restrict__ in, unsigned short* __restrict__ out, int n8) {
  int i = blockIdx.x * blockDim.x + threadIdx.x;
  if (i >= n8) return;
  float4 a = ((const float4*)in)[i * 2];
  float4 b = ((const float4*)in)[i * 2 + 1];
  uint4 o;
  o.x = (unsigned)f2bf(a.x) | ((unsigned)f2bf(a.y) << 16);
  o.y = (unsigned)f2bf(a.z) | ((unsigned)f2bf(a.w) << 16);
  o.z = (unsigned)f2bf(b.x) | ((unsigned)f2bf(b.y) << 16);
  o.w = (unsigned)f2bf(b.z) | ((unsigned)f2bf(b.w) << 16);
  ((uint4*)out)[i] = o;
}

// Wt[r][o][k] (bf16, transposed) = sum_b comp[r,b] * V[b,k,o]
__global__ void compute_w(const float* __restrict__ comp, const float* __restrict__ V,
                          unsigned short* __restrict__ Wt, int IO) {
  int idx = blockIdx.x * blockDim.x + threadIdx.x;
  if (idx >= RELS * IO * HDIM) return;
  int k = idx & (HDIM - 1);
  int o = (idx >> 7) % IO;
  int r = idx / (IO * HDIM);
  float s = 0.f;
#pragma unroll
  for (int b = 0; b < RELS; b++)
    s = fmaf(comp[r * RELS + b], V[(size_t)b * HDIM * IO + (size_t)k * IO + o], s);
  Wt[idx] = f2bf(s);
}

__global__ void hist_bins(const int* __restrict__ dst, const int* __restrict__ etype,
                          int n, int nbins, int* __restrict__ counts) {
  __shared__ int lh[MAXBINS];
  for (int j = threadIdx.x; j < nbins; j += blockDim.x) lh[j] = 0;
  __syncthreads();
  for (int i = blockIdx.x * blockDim.x + threadIdx.x; i < n; i += gridDim.x * blockDim.x)
    atomicAdd(&lh[(dst[i] / DSTBLK) * RELS + etype[i]], 1);
  __syncthreads();
  for (int j = threadIdx.x; j < nbins; j += blockDim.x) {
    int c = lh[j];
    if (c) atomicAdd(&counts[j], c);
  }
}

// exclusive scan of counts padded to multiples of 16 (parallel prefix)
__global__ void scan_offsets(const int* __restrict__ counts, int* __restrict__ offsets, int nbins) {
  __shared__ int csum[256];
  const int t = threadIdx.x;
  const int CH = (nbins + 255) / 256;
  int lo = t * CH, hi = min(lo + CH, nbins);
  int s = 0;
  for (int i = lo; i < hi; i++) s += (counts[i] + 15) & ~15;
  csum[t] = s;
  __syncthreads();
#pragma unroll
  for (int d = 1; d < 256; d <<= 1) {  // Hillis-Steele inclusive scan
    int v = (t >= d) ? csum[t - d] : 0;
    __syncthreads();
    csum[t] += v;
    __syncthreads();
  }
  int run = (t == 0) ? 0 : csum[t - 1];
  for (int i = lo; i < hi; i++) {
    offsets[i] = run;
    run += (counts[i] + 15) & ~15;
  }
  if (lo < nbins && hi == nbins) offsets[nbins] = run;
}

// ebuf[p] = {src | dloc<<20, norm_f32_bits}; dloc = d % DSTBLK (7 bits).
// Pad slots unwritten; all consumers guard by real counts.
__global__ void scatter_bins(const int* __restrict__ src, const int* __restrict__ dst,
                             const int* __restrict__ etype, const float* __restrict__ norm,
                             int n, const int* __restrict__ offsets, int* __restrict__ cursor,
                             uint2* __restrict__ ebuf) {
  for (int i = blockIdx.x * blockDim.x + threadIdx.x; i < n; i += gridDim.x * blockDim.x) {
    int d = dst[i];
    int blk = d / DSTBLK;
    int b = blk * RELS + etype[i];
    int p = offsets[b] + atomicAdd(&cursor[b], 1);
    ebuf[p] = make_uint2((unsigned)src[i] | ((unsigned)(d - blk * DSTBLK) << 20),
                         __float_as_uint(norm[i]));
  }
}

// One block owns DSTBLK nodes; walks a precomputed chunk-descriptor list.
// Per phase ci: (1) issue ebuf loads for ci+3, (2) GEMM1 on xs[cb] -> dacc
// regs, (3) issue gathers for ci+2 from ebuf regs loaded at ci-1,
// (4) scatter: atomicAdd(lds_out[dloc][col], dacc*norm) per valid row,
// (5) write chunk ci+1 xs + {dloc,norm} staging from regs issued at ci-1,
// (6) rotate registers, barrier_nodrain.
// Wave w owns out columns [w*OUT/4, +OUT/4) -> no inter-wave col overlap.
template <int OUT, bool BF16_RELU_OUT>
__launch_bounds__(256, (OUT == 64) ? 4 : 3)
__global__ void rgcn_layer(const unsigned short* __restrict__ Xb,  // [N][128] bf16
                           const unsigned short* __restrict__ Wt,  // [R][OUT][128] bf16
                           const uint2* __restrict__ ebuf,
                           const int* __restrict__ offsets, const int* __restrict__ counts,
                           const float* __restrict__ bias, void* __restrict__ Hout,
                           int nNodes) {
  constexpr int NT = OUT / 64;       // 2 (OUT=128) or 1 (OUT=64)
  constexpr int OSTR = OUT + 4;      // lds_out stride: dloc*4 bank spread
  __shared__ __align__(16) unsigned short xs[2][CHUNK][136];  // gathered src rows
  __shared__ __align__(16) float lds_out[DSTBLK * OSTR];      // f32 accumulator
  __shared__ __align__(16) float normS[2][CHUNK];             // per-row norm (f32)
  __shared__ __align__(4) unsigned char dlocS[2][CHUNK];      // per-row dloc
  __shared__ __align__(8) int2 descS[MAXCH];                  // {base, nRows|rel<<8}
  __shared__ int sBase[16], sCnt[16], sStart[17];

  const int t = threadIdx.x;
  const int w = t >> 6;
  const int lane = t & 63;
  const int quad = lane >> 4;
  const int l16 = lane & 15;
  const int r0 = t >> 4;     // gather row (this thread covers rows r0, r0+16)
  const int k8 = t & 15;     // gather 8-elem column piece
  const int nodeBase = blockIdx.x * DSTBLK;
  const int binBase = blockIdx.x * RELS;
  const int colBase = w * (OUT / 4);

  // zero the accumulator (xs needs no zeroing: stale rows are masked per-lane
  // at the ds_add, and MFMA row r output depends only on A row r)
  for (int i = t; i < DSTBLK * OSTR / 4; i += 256) ((uint4*)lds_out)[i] = make_uint4(0, 0, 0, 0);

  // build chunk descriptor list (bins in relation order -> few W reloads)
  if (t < 16) {
    sBase[t] = offsets[binBase + t];
    sCnt[t] = counts[binBase + t];
  }
  __syncthreads();  // covers lds_out zero + sBase/sCnt (nothing in flight yet)
  if (t == 0) {
    int run = 0;
#pragma unroll
    for (int b = 0; b < 16; b++) {
      sStart[b] = run;
      run += (sCnt[b] + CHUNK - 1) / CHUNK;
    }
    sStart[16] = min(run, MAXCH);
  }
  __syncthreads();
  if (t < 16) {
    int st = sStart[t], ba = sBase[t], c = sCnt[t];
    for (int j = 0; j * CHUNK < c; j++)
      if (st + j < MAXCH)
        descS[st + j] = make_int2(ba + j * CHUNK, min(CHUNK, c - j * CHUNK) | (t << 8));
  }
  __syncthreads();
  const int nCh = sStart[16];

  // pipeline registers (live across barriers)
  uint2 EnE0, EnE1;    // ebuf entries for chunk ci+1 (landed)
  uint2 En2E0, En2E1;  // ebuf entries for chunk ci+2 (in flight ~1 phase)
  uint4 GnG0, GnG1;    // gathered rows for chunk ci+1 (in flight ~1 phase)
  int n1 = 0, n2 = 0;  // nRows of chunks ci+1, ci+2

  // prologue: stage chunk 0 into xs[0]/dn[0]; prime the pipeline regs
  if (nCh > 0) {
    int2 d0 = descS[0];
    int2 d1 = (nCh > 1) ? descS[1] : make_int2(0, 0);
    int2 d2 = (nCh > 2) ? descS[2] : make_int2(0, 0);
    const int rows0 = d0.y & 0xFF;
    n1 = d1.y & 0xFF;
    n2 = d2.y & 0xFF;
    uint2 a0, a1;
    if (r0 < rows0) a0 = ebuf[d0.x + r0];
    if (16 + r0 < rows0) a1 = ebuf[d0.x + 16 + r0];
    if (r0 < n1) EnE0 = ebuf[d1.x + r0];
    if (16 + r0 < n1) EnE1 = ebuf[d1.x + 16 + r0];
    if (r0 < n2) En2E0 = ebuf[d2.x + r0];
    if (16 + r0 < n2) En2E1 = ebuf[d2.x + 16 + r0];
    // gather + write chunk 0 (full latency exposed once per block)
    if (r0 < rows0) {
      *(uint4*)&xs[0][r0][k8 * 8] =
          *(const uint4*)(Xb + (size_t)(a0.x & 0xFFFFFu) * HDIM + k8 * 8);
      if (k8 == 0) {
        dlocS[0][r0] = (unsigned char)((a0.x >> 20) & 127u);
        normS[0][r0] = __uint_as_float(a0.y);
      }
    }
    if (16 + r0 < rows0) {
      *(uint4*)&xs[0][16 + r0][k8 * 8] =
          *(const uint4*)(Xb + (size_t)(a1.x & 0xFFFFFu) * HDIM + k8 * 8);
      if (k8 == 0) {
        dlocS[0][16 + r0] = (unsigned char)((a1.x >> 20) & 127u);
        normS[0][16 + r0] = __uint_as_float(a1.y);
      }
    }
    // issue gathers for chunk 1 (EnE* landed or nearly so by now)
    if (r0 < n1) GnG0 = *(const uint4*)(Xb + (size_t)(EnE0.x & 0xFFFFFu) * HDIM + k8 * 8);
    if (16 + r0 < n1) GnG1 = *(const uint4*)(Xb + (size_t)(EnE1.x & 0xFFFFFu) * HDIM + k8 * 8);
  }
  barrier_nodrain();  // GnG/En2 prefetches must stay in flight

  int cb = 0;
  int curRel = -1;
  bf16x8 wf[4][NT];

  for (int ci = 0; ci < nCh; ci++) {
    int2 dc = descS[ci];
    const int nRows = dc.y & 0xFF;
    const int rel = dc.y >> 8;

    if (rel != curRel) {  // W fragments for this relation (register-resident)
      curRel = rel;
      const unsigned short* Wr = Wt + (size_t)rel * OUT * HDIM;
#pragma unroll
      for (int ks = 0; ks < 4; ks++)
#pragma unroll
        for (int nt = 0; nt < NT; nt++)
          wf[ks][nt] = *(const bf16x8*)(Wr + (size_t)(colBase + nt * 16 + l16) * HDIM + ks * 32 + quad * 8);
    }

    // ---- (1) issue ebuf loads for chunk ci+3 (consumed at ci+1) ----
    int2 d3 = make_int2(0, 0);
    if (ci + 3 < nCh) d3 = descS[ci + 3];
    const int rows3 = d3.y & 0xFF;
    uint2 EwE0, EwE1;
    if (r0 < rows3) EwE0 = ebuf[d3.x + r0];
    if (16 + r0 < rows3) EwE1 = ebuf[d3.x + 16 + r0];

    // ---- (2) GEMM1: dacc = xs[cb] @ W_r (f32, stays in registers) ----
    f32x4 dacc[2][NT];
#pragma unroll
    for (int mt = 0; mt < 2; mt++) {
#pragma unroll
      for (int nt = 0; nt < NT; nt++) dacc[mt][nt] = (f32x4){0.f, 0.f, 0.f, 0.f};
      if (mt * 16 < nRows) {  // wave-uniform
        __builtin_amdgcn_s_setprio(1);
#pragma unroll
        for (int ks = 0; ks < 4; ks++) {
          bf16x8 a = *(const bf16x8*)&xs[cb][mt * 16 + l16][ks * 32 + quad * 8];
#pragma unroll
          for (int nt = 0; nt < NT; nt++)
            dacc[mt][nt] = __builtin_amdgcn_mfma_f32_16x16x32_bf16(a, wf[ks][nt], dacc[mt][nt], 0, 0, 0);
        }
        __builtin_amdgcn_s_setprio(0);
      }
    }

    // ---- (3) issue gathers for chunk ci+2 (ebuf regs landed ~1 phase ago) ----
    uint4 GwG0, GwG1;
    if (r0 < n2) GwG0 = *(const uint4*)(Xb + (size_t)(En2E0.x & 0xFFFFFu) * HDIM + k8 * 8);
    if (16 + r0 < n2) GwG1 = *(const uint4*)(Xb + (size_t)(En2E1.x & 0xFFFFFu) * HDIM + k8 * 8);

    // ---- (4) scatter-add: lds_out[dloc][col] += dacc * norm (f32 atomics) ----
    // dacc row layout: row = mt*16 + quad*4 + reg, col = colBase + nt*16 + l16.
    // Stale/pad rows masked per-lane. ~2-way bank aliasing via OSTR pad = free.
#pragma unroll
    for (int mt = 0; mt < 2; mt++) {
      if (mt * 16 < nRows) {  // wave-uniform
        unsigned dl4 = *(const unsigned*)&dlocS[cb][mt * 16 + quad * 4];
        f32x4 nv = *(const f32x4*)&normS[cb][mt * 16 + quad * 4];
#pragma unroll
        for (int reg = 0; reg < 4; reg++) {
          int row = mt * 16 + quad * 4 + reg;
          if (row < nRows) {
            int dloc = (int)((dl4 >> (8 * reg)) & 127u);
            float nm = nv[reg];
#pragma unroll
            for (int nt = 0; nt < NT; nt++)
              atomicAdd(&lds_out[dloc * OSTR + colBase + nt * 16 + l16],
                        dacc[mt][nt][reg] * nm);
          }
        }
      }
    }

    // ---- (5) write chunk ci+1 into the other xs buffer + dn staging ----
    if (r0 < n1) {
      *(uint4*)&xs[cb ^ 1][r0][k8 * 8] = GnG0;
      if (k8 == 0) {
        dlocS[cb ^ 1][r0] = (unsigned char)((EnE0.x >> 20) & 127u);
        normS[cb ^ 1][r0] = __uint_as_float(EnE0.y);
      }
    }
    if (16 + r0 < n1) {
      *(uint4*)&xs[cb ^ 1][16 + r0][k8 * 8] = GnG1;
      if (k8 == 0) {
        dlocS[cb ^ 1][16 + r0] = (unsigned char)((EnE1.x >> 20) & 127u);
        normS[cb ^ 1][16 + r0] = __uint_as_float(EnE1.y);
      }
    }

    // ---- (6) rotate pipeline registers ----
    EnE0 = En2E0; EnE1 = En2E1;
    En2E0 = EwE0; En2E1 = EwE1;
    GnG0 = GwG0; GnG1 = GwG1;
    n1 = n2; n2 = rows3;

    if (ci + 1 < nCh) barrier_nodrain();  // block-uniform condition
    cb ^= 1;
  }

  __syncthreads();  // all ds_adds visible (end-of-kernel drain is fine)

  // epilogue: read f32 accumulator, add bias, store
  if (BF16_RELU_OUT) {
#pragma unroll 2
    for (int i = t; i < DSTBLK * (OUT / 4); i += 256) {
      int node = i / (OUT / 4);
      int col4 = (i % (OUT / 4)) * 4;
      if (nodeBase + node < nNodes) {
        f32x4 v = *(const f32x4*)&lds_out[node * OSTR + col4];
        float4 b = *(const float4*)&bias[col4];
        uint2 pk;
        pk.x = (unsigned)f2bf(fmaxf(v[0] + b.x, 0.f)) | ((unsigned)f2bf(fmaxf(v[1] + b.y, 0.f)) << 16);
        pk.y = (unsigned)f2bf(fmaxf(v[2] + b.z, 0.f)) | ((unsigned)f2bf(fmaxf(v[3] + b.w, 0.f)) << 16);
        *(uint2*)&((unsigned short*)Hout)[(size_t)(nodeBase + node) * OUT + col4] = pk;
      }
    }
  } else {
#pragma unroll 2
    for (int i = t; i < DSTBLK * (OUT / 4); i += 256) {
      int node = i / (OUT / 4);
      int col4 = (i % (OUT / 4)) * 4;
      if (nodeBase + node < nNodes) {
        f32x4 v = *(const f32x4*)&lds_out[node * OSTR + col4];
        float4 b = *(const float4*)&bias[col4];
        float4 o = make_float4(v[0] + b.x, v[1] + b.y, v[2] + b.z, v[3] + b.w);
        *(float4*)&((float*)Hout)[(size_t)(nodeBase + node) * OUT + col4] = o;
      }
    }
  }
}

extern "C" void kernel_launch(void* const* d_in, const int* in_sizes, int n_in,
                              void* d_out, int out_size, void* d_ws, size_t ws_size,
                              hipStream_t stream) {
  const int*   src   = (const int*)d_in[1];
  const int*   dst   = (const int*)d_in[2];
  const int*   etype = (const int*)d_in[3];
  const float* norm  = (const float*)d_in[4];
  const float* emb   = (const float*)d_in[5];
  const float* V1    = (const float*)d_in[6];
  const float* comp1 = (const float*)d_in[7];
  const float* bias1 = (const float*)d_in[8];
  const float* V2    = (const float*)d_in[9];
  const float* comp2 = (const float*)d_in[10];
  const float* bias2 = (const float*)d_in[11];
  float* out = (float*)d_out;

  const int N = in_sizes[0];  // 50000
  const int E = in_sizes[1];  // 1000000
  const int H = 128, O = 64;
  const int NB = (N + DSTBLK - 1) / DSTBLK;  // 758
  const int NBINS = NB * RELS;               // 12128
  const int EPAD_MAX = E + NBINS * 16;

  char* ws = (char*)d_ws;
  size_t off = 0;
  auto alloc = [&](size_t bytes) -> void* {
    void* p = ws + off;
    off += (bytes + 255) & ~(size_t)255;
    return p;
  };
  unsigned short* W1t  = (unsigned short*)alloc(sizeof(short) * RELS * H * H);
  unsigned short* W2t  = (unsigned short*)alloc(sizeof(short) * RELS * O * H);
  unsigned short* embh = (unsigned short*)alloc(sizeof(short) * (size_t)N * H);
  unsigned short* h1b  = (unsigned short*)alloc(sizeof(short) * (size_t)N * H);
  uint2* ebuf = (uint2*)alloc(sizeof(uint2) * EPAD_MAX);
  int* counts  = (int*)alloc(sizeof(int) * NBINS);
  int* cursor  = (int*)alloc(sizeof(int) * NBINS);
  int* offsets = (int*)alloc(sizeof(int) * (NBINS + 1));

  hipMemsetAsync(counts, 0, sizeof(int) * NBINS, stream);
  hipMemsetAsync(cursor, 0, sizeof(int) * NBINS, stream);

  cvt_bf16<<<((size_t)N * H / 8 + 255) / 256, 256, 0, stream>>>(emb, embh, N * H / 8);
  compute_w<<<(RELS * H * H + 255) / 256, 256, 0, stream>>>(comp1, V1, W1t, H);
  compute_w<<<(RELS * O * H + 255) / 256, 256, 0, stream>>>(comp2, V2, W2t, O);
  hist_bins<<<256, 256, 0, stream>>>(dst, etype, E, NBINS, counts);
  scan_offsets<<<1, 256, 0, stream>>>(counts, offsets, NBINS);
  scatter_bins<<<1024, 256, 0, stream>>>(src, dst, etype, norm, E, offsets, cursor, ebuf);

  rgcn_layer<128, true><<<NB, 256, 0, stream>>>(embh, W1t, ebuf, offsets, counts, bias1, (void*)h1b, N);
  rgcn_layer<64, false><<<NB, 256, 0, stream>>>(h1b, W2t, ebuf, offsets, counts, bias2, (void*)out, N);
}

// Round 4
// 573.428 us; speedup vs baseline: 2.3267x; 2.3267x over previous
//
#include <hip/hip_runtime.h>

// ---------------------------------------------------------------------------
// RGCN (basis decomposition), 2 layers. N=50000, E=1e6, H=128, O=64, R=16.
// Round 13: round 12 (LDS f32 atomics) was a 6x disaster (~190cy per LDS
// atomic instr, all pipes idle) -> REVERTED to round 11's pmat-MFMA scatter.
// Round 11 analysis: ~25 DS instr/wave/phase x 12 waves saturates the shared
// per-CU LDS pipe (~2900cy demand vs 2000cy phase wall) -> LDS-throughput
// bound, which also explains layer2 time == layer1 time and the null result
// of the no-drain barrier.
// Change: ELIMINATE xs (the largest LDS consumer: 8 ds_read_b128 + 2
// ds_write_b128 per wave-phase). The MFMA A-fragment is per-lane
// {row=l16, k=ks*32+quad*8}: load it DIRECTLY from global Xb[src[row]] as
// 8x16B per wave per chunk (+2 per-lane ebuf-entry loads). 4-way inter-wave
// redundancy is served by L1/L2 (same addrs, same window). ebuf row-entry
// loads are min-clamped into the real bin range -> always valid finite rows;
// pad edges still killed by pmat==0. LDS drops 42.5KB -> ~24KB.
// Kept bit-identical to round 11: ys/pmat/agg-MFMA/handler scatter, W-frag
// cache, barrier_nodrain, setprio, epilogue. Depth-2 pipeline: ebuf entries
// (ci+2) and A-frags (ci+1) prefetched; handler em depth-3 as before.
// ---------------------------------------------------------------------------

typedef short bf16x8 __attribute__((ext_vector_type(8)));
typedef float f32x4 __attribute__((ext_vector_type(4)));

#define RELS 16
#define HDIM 128
#define DSTBLK 66
#define MT_P 5    // ceil(66/16): pmat has 80 rows
#define CHUNK 32
#define MAXBINS 12288
#define MAXCH 96  // chunks/block: mean ~49; needs edges>2592 (35 sigma) to overflow

__device__ inline unsigned short f2bf(float f) {
  unsigned int u = __float_as_uint(f);
  unsigned int r = u + 0x7FFFu + ((u >> 16) & 1u);
  return (unsigned short)(r >> 16);
}

// Workgroup barrier WITHOUT the vmcnt(0) drain __syncthreads() emits.
// Correct here because inter-wave communication is exclusively through LDS:
// lgkmcnt(0) makes all DS writes visible; in-flight global loads only feed
// this wave's registers (compiler inserts counted vmcnt at first use).
__device__ inline void barrier_nodrain() {
  __builtin_amdgcn_sched_barrier(0);
  asm volatile("s_waitcnt lgkmcnt(0)" ::: "memory");
  __builtin_amdgcn_s_barrier();
  __builtin_amdgcn_sched_barrier(0);
}

__global__ void cvt_bf16(const float* __restrict__ in, unsigned short* __restrict__ out, int n8) {
  int i = blockIdx.x * blockDim.x + threadIdx.x;
  if (i >= n8) return;
  float4 a = ((const float4*)in)[i * 2];
  float4 b = ((const float4*)in)[i * 2 + 1];
  uint4 o;
  o.x = (unsigned)f2bf(a.x) | ((unsigned)f2bf(a.y) << 16);
  o.y = (unsigned)f2bf(a.z) | ((unsigned)f2bf(a.w) << 16);
  o.z = (unsigned)f2bf(b.x) | ((unsigned)f2bf(b.y) << 16);
  o.w = (unsigned)f2bf(b.z) | ((unsigned)f2bf(b.w) << 16);
  ((uint4*)out)[i] = o;
}

// Wt[r][o][k] (bf16, transposed) = sum_b comp[r,b] * V[b,k,o]
__global__ void compute_w(const float* __restrict__ comp, const float* __restrict__ V,
                          unsigned short* __restrict__ Wt, int IO) {
  int idx = blockIdx.x * blockDim.x + threadIdx.x;
  if (idx >= RELS * IO * HDIM) return;
  int k = idx & (HDIM - 1);
  int o = (idx >> 7) % IO;
  int r = idx / (IO * HDIM);
  float s = 0.f;
#pragma unroll
  for (int b = 0; b < RELS; b++)
    s = fmaf(comp[r * RELS + b], V[(size_t)b * HDIM * IO + (size_t)k * IO + o], s);
  Wt[idx] = f2bf(s);
}

__global__ void hist_bins(const int* __restrict__ dst, const int* __restrict__ etype,
                          int n, int nbins, int* __restrict__ counts) {
  __shared__ int lh[MAXBINS];
  for (int j = threadIdx.x; j < nbins; j += blockDim.x) lh[j] = 0;
  __syncthreads();
  for (int i = blockIdx.x * blockDim.x + threadIdx.x; i < n; i += gridDim.x * blockDim.x)
    atomicAdd(&lh[(dst[i] / DSTBLK) * RELS + etype[i]], 1);
  __syncthreads();
  for (int j = threadIdx.x; j < nbins; j += blockDim.x) {
    int c = lh[j];
    if (c) atomicAdd(&counts[j], c);
  }
}

// exclusive scan of counts padded to multiples of 16 (parallel prefix)
__global__ void scan_offsets(const int* __restrict__ counts, int* __restrict__ offsets, int nbins) {
  __shared__ int csum[256];
  const int t = threadIdx.x;
  const int CH = (nbins + 255) / 256;
  int lo = t * CH, hi = min(lo + CH, nbins);
  int s = 0;
  for (int i = lo; i < hi; i++) s += (counts[i] + 15) & ~15;
  csum[t] = s;
  __syncthreads();
#pragma unroll
  for (int d = 1; d < 256; d <<= 1) {  // Hillis-Steele inclusive scan
    int v = (t >= d) ? csum[t - d] : 0;
    __syncthreads();
    csum[t] += v;
    __syncthreads();
  }
  int run = (t == 0) ? 0 : csum[t - 1];
  for (int i = lo; i < hi; i++) {
    offsets[i] = run;
    run += (counts[i] + 15) & ~15;
  }
  if (lo < nbins && hi == nbins) offsets[nbins] = run;
}

// ebuf[p] = {src | dloc<<20, norm_f32_bits}; dloc = d % DSTBLK (7 bits).
// Pad slots unwritten; all consumers guard/clamp by real counts.
__global__ void scatter_bins(const int* __restrict__ src, const int* __restrict__ dst,
                             const int* __restrict__ etype, const float* __restrict__ norm,
                             int n, const int* __restrict__ offsets, int* __restrict__ cursor,
                             uint2* __restrict__ ebuf) {
  for (int i = blockIdx.x * blockDim.x + threadIdx.x; i < n; i += gridDim.x * blockDim.x) {
    int d = dst[i];
    int blk = d / DSTBLK;
    int b = blk * RELS + etype[i];
    int p = offsets[b] + atomicAdd(&cursor[b], 1);
    ebuf[p] = make_uint2((unsigned)src[i] | ((unsigned)(d - blk * DSTBLK) << 20),
                         __float_as_uint(norm[i]));
  }
}

// One block owns DSTBLK nodes; walks a precomputed chunk-descriptor list.
// Per phase ci: (1) issue per-lane ebuf row-entry loads for ci+2 + handler
// em for ci+3, (2) GEMM1 using register A-fragments (loaded direct from
// global at ci-1) -> pack to ys, (3) issue A-fragment loads for ci+1 from
// Erow regs, (4) agg MFMA pacc += P(pmat) @ ys, (5) handler writes pmat for
// ci+1, (6) rotate, barrier_nodrain. No xs staging at all.
// Wave w owns out columns [w*OUT/4, +OUT/4).
template <int OUT, bool BF16_RELU_OUT>
__launch_bounds__(256, (OUT == 64) ? 4 : 3)
__global__ void rgcn_layer(const unsigned short* __restrict__ Xb,  // [N][128] bf16
                           const unsigned short* __restrict__ Wt,  // [R][OUT][128] bf16
                           const uint2* __restrict__ ebuf,
                           const int* __restrict__ offsets, const int* __restrict__ counts,
                           const float* __restrict__ bias, void* __restrict__ Hout,
                           int nNodes) {
  constexpr int NT = OUT / 64;  // 2 (OUT=128) or 1 (OUT=64)
  __shared__ __align__(16) unsigned short ys[OUT][40];       // messages^T, wave-local cols
  __shared__ __align__(16) unsigned short pmat[2][80][40];   // P[dloc][edge] = bf16(norm)
  __shared__ __align__(8) int2 descS[MAXCH];                 // {base, nRows|rel<<8}
  __shared__ int sBase[16], sCnt[16], sStart[17];

  const int t = threadIdx.x;
  const int w = t >> 6;
  const int lane = t & 63;
  const int quad = lane >> 4;
  const int l16 = lane & 15;
  const bool isHandler = (t & 7) == 0;
  const int myCol = t >> 3;  // handler-owned edge column (0..31, fixed)
  const int nodeBase = blockIdx.x * DSTBLK;
  const int binBase = blockIdx.x * RELS;
  const int colBase = w * (OUT / 4);

  // one-time zero (stale LDS may hold NaN bit patterns; 0 * NaN = NaN)
  for (int i = t; i < OUT * 40 / 8; i += 256) ((uint4*)ys)[i] = make_uint4(0, 0, 0, 0);
  for (int i = t; i < 2 * 80 * 40 / 8; i += 256) ((uint4*)pmat)[i] = make_uint4(0, 0, 0, 0);

  // build chunk descriptor list (bins in relation order -> few W reloads)
  if (t < 16) {
    sBase[t] = offsets[binBase + t];
    sCnt[t] = counts[binBase + t];
  }
  __syncthreads();  // covers zero-init + sBase/sCnt (nothing in flight yet)
  if (t == 0) {
    int run = 0;
#pragma unroll
    for (int b = 0; b < 16; b++) {
      sStart[b] = run;
      run += (sCnt[b] + CHUNK - 1) / CHUNK;
    }
    sStart[16] = min(run, MAXCH);
  }
  __syncthreads();
  if (t < 16) {
    int st = sStart[t], ba = sBase[t], c = sCnt[t];
    for (int j = 0; j * CHUNK < c; j++)
      if (st + j < MAXCH)
        descS[st + j] = make_int2(ba + j * CHUNK, min(CHUNK, c - j * CHUNK) | (t << 8));
  }
  __syncthreads();
  const int nCh = sStart[16];

  f32x4 pacc[MT_P][NT] = {};  // persistent dst accumulator

  // pipeline registers (live across barriers)
  bf16x8 Af[2][4];     // A fragments for chunk ci (row = mt*16+l16, k = ks*32+quad*8)
  uint2 Erow[2];       // ebuf row entries for chunk ci+1 (per-lane row mt*16+l16)
  uint2 EnEm, En2Em;   // handler em for ci+1 (landed), ci+2 (in flight)
  int n1 = 0;          // nRows of chunk ci+1
  int pdA = -1, pdB = -1;  // handler prev-entry trackers (pdA = buffer written next)

  // prologue: A(0) direct loads + prime Erow(1)/em(1)/em(2); pmat[0] writes
  if (nCh > 0) {
    int2 d0 = descS[0];
    int2 d1 = (nCh > 1) ? descS[1] : make_int2(0, 0);
    int2 d2 = (nCh > 2) ? descS[2] : make_int2(0, 0);
    const int rows0 = d0.y & 0xFF;
    n1 = d1.y & 0xFF;
    const int rows2 = d2.y & 0xFF;
    uint2 E0[2];
#pragma unroll
    for (int mt = 0; mt < 2; mt++) {
      int row = mt * 16 + l16;
      E0[mt] = ebuf[d0.x + min(row, rows0 - 1)];  // rows0 >= 1 for an existing chunk
      if (n1 > 0) Erow[mt] = ebuf[d1.x + min(row, n1 - 1)];
    }
    uint2 am;
    if (isHandler) {
      if (myCol < rows0) am = ebuf[d0.x + myCol];
      if (myCol < n1) EnEm = ebuf[d1.x + myCol];
      if (myCol < rows2) En2Em = ebuf[d2.x + myCol];
    }
#pragma unroll
    for (int mt = 0; mt < 2; mt++) {
      const unsigned short* p = Xb + (size_t)(E0[mt].x & 0xFFFFFu) * HDIM + quad * 8;
#pragma unroll
      for (int ks = 0; ks < 4; ks++) Af[mt][ks] = *(const bf16x8*)(p + ks * 32);
    }
    if (isHandler && myCol < rows0) {
      int dl = (int)(am.x >> 20) & 127;
      pmat[0][dl][myCol] = f2bf(__uint_as_float(am.y));
      pdB = dl;  // buffer-0 tracker; first loop phase writes buffer 1 via pdA
    }
  }
  barrier_nodrain();  // A(0)/Erow/em prefetches stay in flight

  int cb = 0;
  int curRel = -1;
  bf16x8 wf[4][NT];

  for (int ci = 0; ci < nCh; ci++) {
    int2 dc = descS[ci];
    const int nRows = dc.y & 0xFF;
    const int rel = dc.y >> 8;

    if (rel != curRel) {  // W fragments for this relation (register-resident)
      curRel = rel;
      const unsigned short* Wr = Wt + (size_t)rel * OUT * HDIM;
#pragma unroll
      for (int ks = 0; ks < 4; ks++)
#pragma unroll
        for (int nt = 0; nt < NT; nt++)
          wf[ks][nt] = *(const bf16x8*)(Wr + (size_t)(colBase + nt * 16 + l16) * HDIM + ks * 32 + quad * 8);
    }

    // ---- (1) issue ebuf row entries for ci+2 and handler em for ci+3 ----
    int2 d2 = (ci + 2 < nCh) ? descS[ci + 2] : make_int2(0, 0);
    int2 d3 = (ci + 3 < nCh) ? descS[ci + 3] : make_int2(0, 0);
    const int n2 = d2.y & 0xFF;
    const int n3 = d3.y & 0xFF;
    uint2 ErowN[2];
    if (n2 > 0) {
#pragma unroll
      for (int mt = 0; mt < 2; mt++)
        ErowN[mt] = ebuf[d2.x + min(mt * 16 + l16, n2 - 1)];
    }
    uint2 EwEm;
    if (isHandler && myCol < n3) EwEm = ebuf[d3.x + myCol];

    // ---- (2) GEMM1: dacc = A(ci) @ W_r (A from registers), pack -> ys ----
#pragma unroll
    for (int mt = 0; mt < 2; mt++) {
      if (mt * 16 < nRows) {  // wave-uniform
        f32x4 dacc[NT] = {};
        __builtin_amdgcn_s_setprio(1);
#pragma unroll
        for (int ks = 0; ks < 4; ks++) {
#pragma unroll
          for (int nt = 0; nt < NT; nt++)
            dacc[nt] = __builtin_amdgcn_mfma_f32_16x16x32_bf16(Af[mt][ks], wf[ks][nt], dacc[nt], 0, 0, 0);
        }
        __builtin_amdgcn_s_setprio(0);
#pragma unroll
        for (int nt = 0; nt < NT; nt++) {
          uint2 pk;
          pk.x = (unsigned)f2bf(dacc[nt][0]) | ((unsigned)f2bf(dacc[nt][1]) << 16);
          pk.y = (unsigned)f2bf(dacc[nt][2]) | ((unsigned)f2bf(dacc[nt][3]) << 16);
          *(uint2*)&ys[colBase + nt * 16 + l16][mt * 16 + quad * 4] = pk;
        }
      }
    }

    // ---- (3) issue A-fragment loads for chunk ci+1 (overwrite Af; WAR safe:
    //          GEMM above already consumed Af at issue) ----
    if (n1 > 0) {
#pragma unroll
      for (int mt = 0; mt < 2; mt++) {
        const unsigned short* p = Xb + (size_t)(Erow[mt].x & 0xFFFFFu) * HDIM + quad * 8;
#pragma unroll
        for (int ks = 0; ks < 4; ks++) Af[mt][ks] = *(const bf16x8*)(p + ks * 32);
      }
    }

    // ---- (4) aggregation GEMM: pacc += P(norm) @ Y (single k=32 pass) ----
    // pmat[cb] barrier-protected; ys wave-local (same-wave LDS RAW in-order);
    // stale ys edge-columns have pmat == 0.
    {
      bf16x8 bfv[NT];
#pragma unroll
      for (int nt = 0; nt < NT; nt++)
        bfv[nt] = *(const bf16x8*)&ys[colBase + nt * 16 + l16][quad * 8];
      __builtin_amdgcn_s_setprio(1);
#pragma unroll
      for (int mt = 0; mt < MT_P; mt++) {
        bf16x8 a = *(const bf16x8*)&pmat[cb][mt * 16 + l16][quad * 8];
#pragma unroll
        for (int nt = 0; nt < NT; nt++)
          pacc[mt][nt] = __builtin_amdgcn_mfma_f32_16x16x32_bf16(a, bfv[nt], pacc[mt][nt], 0, 0, 0);
      }
      __builtin_amdgcn_s_setprio(0);
    }

    // ---- (5) handler: write pmat for chunk ci+1 into the other buffer ----
    if (isHandler) {
      if (pdA >= 0) pmat[cb ^ 1][pdA][myCol] = 0;  // clear own old entry
      if (myCol < n1) {
        int dl = (int)(EnEm.x >> 20) & 127;
        pmat[cb ^ 1][dl][myCol] = f2bf(__uint_as_float(EnEm.y));
        pdA = dl;
      } else {
        pdA = -1;
      }
    }
    { int tmp = pdA; pdA = pdB; pdB = tmp; }  // tracker follows buffer parity

    // ---- (6) rotate pipeline registers ----
    Erow[0] = ErowN[0]; Erow[1] = ErowN[1];
    EnEm = En2Em; En2Em = EwEm;
    n1 = n2;

    if (ci + 1 < nCh) barrier_nodrain();  // block-uniform condition
    cb ^= 1;
  }

  // epilogue: each (node, col) owned by exactly one lane -> plain stores
#pragma unroll
  for (int mt = 0; mt < MT_P; mt++) {
#pragma unroll
    for (int reg = 0; reg < 4; reg++) {
      int ld = mt * 16 + quad * 4 + reg;
      int node = nodeBase + ld;
      if (ld < DSTBLK && node < nNodes) {
#pragma unroll
        for (int nt = 0; nt < NT; nt++) {
          int col = colBase + nt * 16 + l16;
          float v = pacc[mt][nt][reg] + bias[col];
          if constexpr (BF16_RELU_OUT)
            ((unsigned short*)Hout)[(size_t)node * OUT + col] = f2bf(fmaxf(v, 0.f));
          else
            ((float*)Hout)[(size_t)node * OUT + col] = v;
        }
      }
    }
  }
}

extern "C" void kernel_launch(void* const* d_in, const int* in_sizes, int n_in,
                              void* d_out, int out_size, void* d_ws, size_t ws_size,
                              hipStream_t stream) {
  const int*   src   = (const int*)d_in[1];
  const int*   dst   = (const int*)d_in[2];
  const int*   etype = (const int*)d_in[3];
  const float* norm  = (const float*)d_in[4];
  const float* emb   = (const float*)d_in[5];
  const float* V1    = (const float*)d_in[6];
  const float* comp1 = (const float*)d_in[7];
  const float* bias1 = (const float*)d_in[8];
  const float* V2    = (const float*)d_in[9];
  const float* comp2 = (const float*)d_in[10];
  const float* bias2 = (const float*)d_in[11];
  float* out = (float*)d_out;

  const int N = in_sizes[0];  // 50000
  const int E = in_sizes[1];  // 1000000
  const int H = 128, O = 64;
  const int NB = (N + DSTBLK - 1) / DSTBLK;  // 758
  const int NBINS = NB * RELS;               // 12128
  const int EPAD_MAX = E + NBINS * 16;

  char* ws = (char*)d_ws;
  size_t off = 0;
  auto alloc = [&](size_t bytes) -> void* {
    void* p = ws + off;
    off += (bytes + 255) & ~(size_t)255;
    return p;
  };
  unsigned short* W1t  = (unsigned short*)alloc(sizeof(short) * RELS * H * H);
  unsigned short* W2t  = (unsigned short*)alloc(sizeof(short) * RELS * O * H);
  unsigned short* embh = (unsigned short*)alloc(sizeof(short) * (size_t)N * H);
  unsigned short* h1b  = (unsigned short*)alloc(sizeof(short) * (size_t)N * H);
  uint2* ebuf = (uint2*)alloc(sizeof(uint2) * EPAD_MAX);
  int* counts  = (int*)alloc(sizeof(int) * NBINS);
  int* cursor  = (int*)alloc(sizeof(int) * NBINS);
  int* offsets = (int*)alloc(sizeof(int) * (NBINS + 1));

  hipMemsetAsync(counts, 0, sizeof(int) * NBINS, stream);
  hipMemsetAsync(cursor, 0, sizeof(int) * NBINS, stream);

  cvt_bf16<<<((size_t)N * H / 8 + 255) / 256, 256, 0, stream>>>(emb, embh, N * H / 8);
  compute_w<<<(RELS * H * H + 255) / 256, 256, 0, stream>>>(comp1, V1, W1t, H);
  compute_w<<<(RELS * O * H + 255) / 256, 256, 0, stream>>>(comp2, V2, W2t, O);
  hist_bins<<<256, 256, 0, stream>>>(dst, etype, E, NBINS, counts);
  scan_offsets<<<1, 256, 0, stream>>>(counts, offsets, NBINS);
  scatter_bins<<<1024, 256, 0, stream>>>(src, dst, etype, norm, E, offsets, cursor, ebuf);

  rgcn_layer<128, true><<<NB, 256, 0, stream>>>(embh, W1t, ebuf, offsets, counts, bias1, (void*)h1b, N);
  rgcn_layer<64, false><<<NB, 256, 0, stream>>>(h1b, W2t, ebuf, offsets, counts, bias2, (void*)out, N);
}

// Round 5
// 428.651 us; speedup vs baseline: 3.1126x; 1.3378x over previous
//
#include <hip/hip_runtime.h>

// ---------------------------------------------------------------------------
// RGCN (basis decomposition), 2 layers. N=50000, E=1e6, H=128, O=64, R=16.
// Round 14: round 13 (direct-global A-frags) regressed 123->196us/layer
// (scattered VMEM + 4x wave redundancy; conflicts dropped but time rose) ->
// REVERTED to round 11 structure (xs LDS staging + pmat-MFMA scatter).
// New theory for r11's 2000cy/block-phase wall: the end-of-phase pipeline
// register ROTATION (GnG0=GwG0 etc.) is a USE of same-phase-issued loads ->
// the compiler must insert s_waitcnt vmcnt(~0) before the movs -> full VMEM
// drain every phase regardless of barrier type. Explains r10's small gain,
// r11's null, and the wall arithmetic (chain ~1000cy + exposed ~900cy).
// Change: 2x-UNROLLED phase loop with ping/pong register sets (P/Q).
// All prefetches at depth 2 (produced phase k, consumed k+1): entries ->
// gathers -> xs-write -> GEMM each one phase apart. Even phases read Q
// write P; odd phases reverse. ZERO rotation movs -> vmcnt waits are
// counted at true first use with a full phase of cover. cb is a constant
// per call site (static LDS indexing). Dead EnE0/EnE1 regs removed.
// Kept identical to r11: GEMM1/ys/pmat/agg layouts, handler scatter+clear,
// W-frag cache, barrier_nodrain, setprio, epilogue, preprocessing.
// ---------------------------------------------------------------------------

typedef short bf16x8 __attribute__((ext_vector_type(8)));
typedef float f32x4 __attribute__((ext_vector_type(4)));

#define RELS 16
#define HDIM 128
#define DSTBLK 66
#define MT_P 5    // ceil(66/16): pmat has 80 rows
#define CHUNK 32
#define MAXBINS 12288
#define MAXCH 96  // chunks/block: mean ~49; needs edges>2592 (35 sigma) to overflow

__device__ inline unsigned short f2bf(float f) {
  unsigned int u = __float_as_uint(f);
  unsigned int r = u + 0x7FFFu + ((u >> 16) & 1u);
  return (unsigned short)(r >> 16);
}

// Workgroup barrier WITHOUT the vmcnt(0) drain __syncthreads() emits.
// Correct here because inter-wave communication is exclusively through LDS:
// lgkmcnt(0) makes all DS writes visible; in-flight global loads only feed
// this wave's registers (compiler inserts counted vmcnt at first use).
__device__ inline void barrier_nodrain() {
  __builtin_amdgcn_sched_barrier(0);
  asm volatile("s_waitcnt lgkmcnt(0)" ::: "memory");
  __builtin_amdgcn_s_barrier();
  __builtin_amdgcn_sched_barrier(0);
}

__global__ void cvt_bf16(const float* __restrict__ in, unsigned short* __restrict__ out, int n8) {
  int i = blockIdx.x * blockDim.x + threadIdx.x;
  if (i >= n8) return;
  float4 a = ((const float4*)in)[i * 2];
  float4 b = ((const float4*)in)[i * 2 + 1];
  uint4 o;
  o.x = (unsigned)f2bf(a.x) | ((unsigned)f2bf(a.y) << 16);
  o.y = (unsigned)f2bf(a.z) | ((unsigned)f2bf(a.w) << 16);
  o.z = (unsigned)f2bf(b.x) | ((unsigned)f2bf(b.y) << 16);
  o.w = (unsigned)f2bf(b.z) | ((unsigned)f2bf(b.w) << 16);
  ((uint4*)out)[i] = o;
}

// Wt[r][o][k] (bf16, transposed) = sum_b comp[r,b] * V[b,k,o]
__global__ void compute_w(const float* __restrict__ comp, const float* __restrict__ V,
                          unsigned short* __restrict__ Wt, int IO) {
  int idx = blockIdx.x * blockDim.x + threadIdx.x;
  if (idx >= RELS * IO * HDIM) return;
  int k = idx & (HDIM - 1);
  int o = (idx >> 7) % IO;
  int r = idx / (IO * HDIM);
  float s = 0.f;
#pragma unroll
  for (int b = 0; b < RELS; b++)
    s = fmaf(comp[r * RELS + b], V[(size_t)b * HDIM * IO + (size_t)k * IO + o], s);
  Wt[idx] = f2bf(s);
}

__global__ void hist_bins(const int* __restrict__ dst, const int* __restrict__ etype,
                          int n, int nbins, int* __restrict__ counts) {
  __shared__ int lh[MAXBINS];
  for (int j = threadIdx.x; j < nbins; j += blockDim.x) lh[j] = 0;
  __syncthreads();
  for (int i = blockIdx.x * blockDim.x + threadIdx.x; i < n; i += gridDim.x * blockDim.x)
    atomicAdd(&lh[(dst[i] / DSTBLK) * RELS + etype[i]], 1);
  __syncthreads();
  for (int j = threadIdx.x; j < nbins; j += blockDim.x) {
    int c = lh[j];
    if (c) atomicAdd(&counts[j], c);
  }
}

// exclusive scan of counts padded to multiples of 16 (parallel prefix)
__global__ void scan_offsets(const int* __restrict__ counts, int* __restrict__ offsets, int nbins) {
  __shared__ int csum[256];
  const int t = threadIdx.x;
  const int CH = (nbins + 255) / 256;
  int lo = t * CH, hi = min(lo + CH, nbins);
  int s = 0;
  for (int i = lo; i < hi; i++) s += (counts[i] + 15) & ~15;
  csum[t] = s;
  __syncthreads();
#pragma unroll
  for (int d = 1; d < 256; d <<= 1) {  // Hillis-Steele inclusive scan
    int v = (t >= d) ? csum[t - d] : 0;
    __syncthreads();
    csum[t] += v;
    __syncthreads();
  }
  int run = (t == 0) ? 0 : csum[t - 1];
  for (int i = lo; i < hi; i++) {
    offsets[i] = run;
    run += (counts[i] + 15) & ~15;
  }
  if (lo < nbins && hi == nbins) offsets[nbins] = run;
}

// ebuf[p] = {src | dloc<<20, norm_f32_bits}; dloc = d % DSTBLK (7 bits).
// Pad slots unwritten; all consumers guard by real counts.
__global__ void scatter_bins(const int* __restrict__ src, const int* __restrict__ dst,
                             const int* __restrict__ etype, const float* __restrict__ norm,
                             int n, const int* __restrict__ offsets, int* __restrict__ cursor,
                             uint2* __restrict__ ebuf) {
  for (int i = blockIdx.x * blockDim.x + threadIdx.x; i < n; i += gridDim.x * blockDim.x) {
    int d = dst[i];
    int blk = d / DSTBLK;
    int b = blk * RELS + etype[i];
    int p = offsets[b] + atomicAdd(&cursor[b], 1);
    ebuf[p] = make_uint2((unsigned)src[i] | ((unsigned)(d - blk * DSTBLK) << 20),
                         __float_as_uint(norm[i]));
  }
}

// One block owns DSTBLK nodes; walks a precomputed chunk-descriptor list.
// Depth-2 pipeline, 2x unrolled with ping/pong register sets (no rotation
// movs). Phase ci (parity = cb): (1) load entries(ci+3) + hentry(ci+2) into
// OUT set, (2) GEMM1 on xs[cb] -> ys, (3) issue gathers(ci+2) from IN
// entries, (4) agg pacc += pmat[cb] @ ys, (5) write xs[cb^1]/pmat[cb^1] for
// chunk ci+1 from IN gathers/hentry, (6) barrier_nodrain.
// Wave w owns out columns [w*OUT/4, +OUT/4).
template <int OUT, bool BF16_RELU_OUT>
__launch_bounds__(256, (OUT == 64) ? 4 : 3)
__global__ void rgcn_layer(const unsigned short* __restrict__ Xb,  // [N][128] bf16
                           const unsigned short* __restrict__ Wt,  // [R][OUT][128] bf16
                           const uint2* __restrict__ ebuf,
                           const int* __restrict__ offsets, const int* __restrict__ counts,
                           const float* __restrict__ bias, void* __restrict__ Hout,
                           int nNodes) {
  constexpr int NT = OUT / 64;  // 2 (OUT=128) or 1 (OUT=64)
  __shared__ __align__(16) unsigned short xs[2][CHUNK][136];  // gathered src rows
  __shared__ __align__(16) unsigned short ys[OUT][40];        // messages^T, wave-local cols
  __shared__ __align__(16) unsigned short pmat[2][80][40];    // P[dloc][edge] = bf16(norm)
  __shared__ __align__(8) int2 descS[MAXCH];                  // {base, nRows|rel<<8}
  __shared__ int sBase[16], sCnt[16], sStart[17];

  const int t = threadIdx.x;
  const int w = t >> 6;
  const int lane = t & 63;
  const int quad = lane >> 4;
  const int l16 = lane & 15;
  const int r0 = t >> 4;     // gather row (this thread covers rows r0, r0+16)
  const int k8 = t & 15;     // gather 8-elem column piece
  const bool isHandler = (t & 7) == 0;
  const int myCol = t >> 3;  // handler-owned edge column (0..31, fixed)
  const int nodeBase = blockIdx.x * DSTBLK;
  const int binBase = blockIdx.x * RELS;
  const int colBase = w * (OUT / 4);

  // one-time zero (stale LDS may hold NaN bit patterns; 0 * NaN = NaN)
  for (int i = t; i < 2 * CHUNK * 136 / 8; i += 256) ((uint4*)xs)[i] = make_uint4(0, 0, 0, 0);
  for (int i = t; i < OUT * 40 / 8; i += 256) ((uint4*)ys)[i] = make_uint4(0, 0, 0, 0);
  for (int i = t; i < 2 * 80 * 40 / 8; i += 256) ((uint4*)pmat)[i] = make_uint4(0, 0, 0, 0);

  // build chunk descriptor list (bins in relation order -> few W reloads)
  if (t < 16) {
    sBase[t] = offsets[binBase + t];
    sCnt[t] = counts[binBase + t];
  }
  __syncthreads();  // covers zero-init + sBase/sCnt (nothing in flight yet)
  if (t == 0) {
    int run = 0;
#pragma unroll
    for (int b = 0; b < 16; b++) {
      sStart[b] = run;
      run += (sCnt[b] + CHUNK - 1) / CHUNK;
    }
    sStart[16] = min(run, MAXCH);
  }
  __syncthreads();
  if (t < 16) {
    int st = sStart[t], ba = sBase[t], c = sCnt[t];
    for (int j = 0; j * CHUNK < c; j++)
      if (st + j < MAXCH)
        descS[st + j] = make_int2(ba + j * CHUNK, min(CHUNK, c - j * CHUNK) | (t << 8));
  }
  __syncthreads();
  const int nCh = sStart[16];

  f32x4 pacc[MT_P][NT] = {};  // persistent dst accumulator

  // ping/pong pipeline register sets (live across one barrier each; no movs)
  struct Pipe {
    uint2 E0, E1;  // ebuf entries (rows r0, 16+r0) for the chunk gathered next phase
    uint4 G0, G1;  // gathered xs rows, written to LDS next phase
    uint2 H;       // handler ebuf entry, written to pmat next phase
  };
  Pipe P, Q;
  int pd0 = -1, pd1 = -1;  // handler prev-entry tracker per pmat buffer
  int n1 = 0, n2 = 0;      // rows(ci+1), rows(ci+2)

  // prologue (acts as phase -1): stage chunk 0; prime Q = {entries(2),
  // gathers(1), hentry(1)}; full latency exposed once per block.
  if (nCh > 0) {
    int2 d0 = descS[0];
    int2 d1 = (nCh > 1) ? descS[1] : make_int2(0, 0);
    int2 d2 = (nCh > 2) ? descS[2] : make_int2(0, 0);
    const int rows0 = d0.y & 0xFF;
    n1 = d1.y & 0xFF;
    n2 = d2.y & 0xFF;
    uint2 a0, a1, am, e10, e11;
    if (r0 < rows0) a0 = ebuf[d0.x + r0];
    if (16 + r0 < rows0) a1 = ebuf[d0.x + 16 + r0];
    if (isHandler && myCol < rows0) am = ebuf[d0.x + myCol];
    if (r0 < n1) e10 = ebuf[d1.x + r0];
    if (16 + r0 < n1) e11 = ebuf[d1.x + 16 + r0];
    if (isHandler && myCol < n1) Q.H = ebuf[d1.x + myCol];
    if (r0 < n2) Q.E0 = ebuf[d2.x + r0];
    if (16 + r0 < n2) Q.E1 = ebuf[d2.x + 16 + r0];
    // stage chunk 0 into xs[0]/pmat[0]
    if (r0 < rows0)
      *(uint4*)&xs[0][r0][k8 * 8] =
          *(const uint4*)(Xb + (size_t)(a0.x & 0xFFFFFu) * HDIM + k8 * 8);
    if (16 + r0 < rows0)
      *(uint4*)&xs[0][16 + r0][k8 * 8] =
          *(const uint4*)(Xb + (size_t)(a1.x & 0xFFFFFu) * HDIM + k8 * 8);
    if (isHandler && myCol < rows0) {
      int dl = (int)(am.x >> 20) & 127;
      pmat[0][dl][myCol] = f2bf(__uint_as_float(am.y));
      pd0 = dl;
    }
    // issue gathers for chunk 1 (e1* landed or nearly so by now)
    if (r0 < n1) Q.G0 = *(const uint4*)(Xb + (size_t)(e10.x & 0xFFFFFu) * HDIM + k8 * 8);
    if (16 + r0 < n1) Q.G1 = *(const uint4*)(Xb + (size_t)(e11.x & 0xFFFFFu) * HDIM + k8 * 8);
  }
  barrier_nodrain();  // Q prefetches stay in flight

  int curRel = -1;
  bf16x8 wf[4][NT];

  // phase body; cbv is a literal 0/1 at each call site -> static LDS indices
  auto phase = [&](int ci, int cbv, Pipe& in, Pipe& out, int n1v, int n2v,
                   int& pdW) -> int {
    int2 dc = descS[ci];
    const int nRows = dc.y & 0xFF;
    const int rel = dc.y >> 8;

    if (rel != curRel) {  // W fragments for this relation (register-resident)
      curRel = rel;
      const unsigned short* Wr = Wt + (size_t)rel * OUT * HDIM;
#pragma unroll
      for (int ks = 0; ks < 4; ks++)
#pragma unroll
        for (int nt = 0; nt < NT; nt++)
          wf[ks][nt] = *(const bf16x8*)(Wr + (size_t)(colBase + nt * 16 + l16) * HDIM + ks * 32 + quad * 8);
    }

    // ---- (1) births: entries(ci+3) -> out.E*, hentry(ci+2) -> out.H ----
    int2 d3 = (ci + 3 < nCh) ? descS[ci + 3] : make_int2(0, 0);
    const int n3 = d3.y & 0xFF;
    if (r0 < n3) out.E0 = ebuf[d3.x + r0];
    if (16 + r0 < n3) out.E1 = ebuf[d3.x + 16 + r0];
    if (isHandler && myCol < n2v) out.H = ebuf[descS[ci + 2].x + myCol];

    // ---- (2) GEMM1: Y = xs[cbv] @ W_r, staged to wave-local ys^T columns ----
#pragma unroll
    for (int mt = 0; mt < 2; mt++) {
      if (mt * 16 < nRows) {  // wave-uniform
        f32x4 dacc[NT] = {};
        __builtin_amdgcn_s_setprio(1);
#pragma unroll
        for (int ks = 0; ks < 4; ks++) {
          bf16x8 a = *(const bf16x8*)&xs[cbv][mt * 16 + l16][ks * 32 + quad * 8];
#pragma unroll
          for (int nt = 0; nt < NT; nt++)
            dacc[nt] = __builtin_amdgcn_mfma_f32_16x16x32_bf16(a, wf[ks][nt], dacc[nt], 0, 0, 0);
        }
        __builtin_amdgcn_s_setprio(0);
#pragma unroll
        for (int nt = 0; nt < NT; nt++) {
          uint2 pk;
          pk.x = (unsigned)f2bf(dacc[nt][0]) | ((unsigned)f2bf(dacc[nt][1]) << 16);
          pk.y = (unsigned)f2bf(dacc[nt][2]) | ((unsigned)f2bf(dacc[nt][3]) << 16);
          *(uint2*)&ys[colBase + nt * 16 + l16][mt * 16 + quad * 4] = pk;
        }
      }
    }

    // ---- (3) issue gathers(ci+2) from IN entries (landed: 1 phase cover) ----
    if (r0 < n2v) out.G0 = *(const uint4*)(Xb + (size_t)(in.E0.x & 0xFFFFFu) * HDIM + k8 * 8);
    if (16 + r0 < n2v) out.G1 = *(const uint4*)(Xb + (size_t)(in.E1.x & 0xFFFFFu) * HDIM + k8 * 8);

    // ---- (4) aggregation GEMM: pacc += P(norm) @ Y (single k=32 pass) ----
    // pmat[cbv] barrier-protected; ys wave-local (same-wave LDS RAW in-order);
    // stale ys edge-columns have pmat == 0.
    {
      bf16x8 bfv[NT];
#pragma unroll
      for (int nt = 0; nt < NT; nt++)
        bfv[nt] = *(const bf16x8*)&ys[colBase + nt * 16 + l16][quad * 8];
      __builtin_amdgcn_s_setprio(1);
#pragma unroll
      for (int mt = 0; mt < MT_P; mt++) {
        bf16x8 a = *(const bf16x8*)&pmat[cbv][mt * 16 + l16][quad * 8];
#pragma unroll
        for (int nt = 0; nt < NT; nt++)
          pacc[mt][nt] = __builtin_amdgcn_mfma_f32_16x16x32_bf16(a, bfv[nt], pacc[mt][nt], 0, 0, 0);
      }
      __builtin_amdgcn_s_setprio(0);
    }

    // ---- (5) write chunk ci+1 from IN gathers/hentry (1 phase of cover;
    //          counted vmcnt here, newer out.* loads stay in flight) ----
    if (r0 < n1v) *(uint4*)&xs[cbv ^ 1][r0][k8 * 8] = in.G0;
    if (16 + r0 < n1v) *(uint4*)&xs[cbv ^ 1][16 + r0][k8 * 8] = in.G1;
    if (isHandler) {
      if (pdW >= 0) pmat[cbv ^ 1][pdW][myCol] = 0;  // clear own old entry
      if (myCol < n1v) {
        int dl = (int)(in.H.x >> 20) & 127;
        pmat[cbv ^ 1][dl][myCol] = f2bf(__uint_as_float(in.H.y));
        pdW = dl;
      } else {
        pdW = -1;
      }
    }

    if (ci + 1 < nCh) barrier_nodrain();  // block-uniform condition
    return n3;
  };

  // 2x-unrolled driver: even phases read Q write P; odd phases reverse.
  int ci = 0;
  while (ci < nCh) {
    int n3 = phase(ci, 0, Q, P, n1, n2, pd1);
    n1 = n2; n2 = n3; ci++;
    if (ci >= nCh) break;
    n3 = phase(ci, 1, P, Q, n1, n2, pd0);
    n1 = n2; n2 = n3; ci++;
  }

  // epilogue: each (node, col) owned by exactly one lane -> plain stores
#pragma unroll
  for (int mt = 0; mt < MT_P; mt++) {
#pragma unroll
    for (int reg = 0; reg < 4; reg++) {
      int ld = mt * 16 + quad * 4 + reg;
      int node = nodeBase + ld;
      if (ld < DSTBLK && node < nNodes) {
#pragma unroll
        for (int nt = 0; nt < NT; nt++) {
          int col = colBase + nt * 16 + l16;
          float v = pacc[mt][nt][reg] + bias[col];
          if constexpr (BF16_RELU_OUT)
            ((unsigned short*)Hout)[(size_t)node * OUT + col] = f2bf(fmaxf(v, 0.f));
          else
            ((float*)Hout)[(size_t)node * OUT + col] = v;
        }
      }
    }
  }
}

extern "C" void kernel_launch(void* const* d_in, const int* in_sizes, int n_in,
                              void* d_out, int out_size, void* d_ws, size_t ws_size,
                              hipStream_t stream) {
  const int*   src   = (const int*)d_in[1];
  const int*   dst   = (const int*)d_in[2];
  const int*   etype = (const int*)d_in[3];
  const float* norm  = (const float*)d_in[4];
  const float* emb   = (const float*)d_in[5];
  const float* V1    = (const float*)d_in[6];
  const float* comp1 = (const float*)d_in[7];
  const float* bias1 = (const float*)d_in[8];
  const float* V2    = (const float*)d_in[9];
  const float* comp2 = (const float*)d_in[10];
  const float* bias2 = (const float*)d_in[11];
  float* out = (float*)d_out;

  const int N = in_sizes[0];  // 50000
  const int E = in_sizes[1];  // 1000000
  const int H = 128, O = 64;
  const int NB = (N + DSTBLK - 1) / DSTBLK;  // 758
  const int NBINS = NB * RELS;               // 12128
  const int EPAD_MAX = E + NBINS * 16;

  char* ws = (char*)d_ws;
  size_t off = 0;
  auto alloc = [&](size_t bytes) -> void* {
    void* p = ws + off;
    off += (bytes + 255) & ~(size_t)255;
    return p;
  };
  unsigned short* W1t  = (unsigned short*)alloc(sizeof(short) * RELS * H * H);
  unsigned short* W2t  = (unsigned short*)alloc(sizeof(short) * RELS * O * H);
  unsigned short* embh = (unsigned short*)alloc(sizeof(short) * (size_t)N * H);
  unsigned short* h1b  = (unsigned short*)alloc(sizeof(short) * (size_t)N * H);
  uint2* ebuf = (uint2*)alloc(sizeof(uint2) * EPAD_MAX);
  int* counts  = (int*)alloc(sizeof(int) * NBINS);
  int* cursor  = (int*)alloc(sizeof(int) * NBINS);
  int* offsets = (int*)alloc(sizeof(int) * (NBINS + 1));

  hipMemsetAsync(counts, 0, sizeof(int) * NBINS, stream);
  hipMemsetAsync(cursor, 0, sizeof(int) * NBINS, stream);

  cvt_bf16<<<((size_t)N * H / 8 + 255) / 256, 256, 0, stream>>>(emb, embh, N * H / 8);
  compute_w<<<(RELS * H * H + 255) / 256, 256, 0, stream>>>(comp1, V1, W1t, H);
  compute_w<<<(RELS * O * H + 255) / 256, 256, 0, stream>>>(comp2, V2, W2t, O);
  hist_bins<<<256, 256, 0, stream>>>(dst, etype, E, NBINS, counts);
  scan_offsets<<<1, 256, 0, stream>>>(counts, offsets, NBINS);
  scatter_bins<<<1024, 256, 0, stream>>>(src, dst, etype, norm, E, offsets, cursor, ebuf);

  rgcn_layer<128, true><<<NB, 256, 0, stream>>>(embh, W1t, ebuf, offsets, counts, bias1, (void*)h1b, N);
  rgcn_layer<64, false><<<NB, 256, 0, stream>>>(h1b, W2t, ebuf, offsets, counts, bias2, (void*)out, N);
}